// Round 2
// baseline (215.468 us; speedup 1.0000x reference)
//
#include <hip/hip_runtime.h>

// Detail_loss: loss = 0.25/(98*258*256) * sum_{n,h,w} ( |D[h][w+1]-D[h][w-1]| + |D[h+1][w]-D[h-1][w]| )
// where D[n,h,w] = sum_c (infer - ref)[n,c,h,w], zero outside [0,256)^2.
// (conv kernels identical across channel pairs -> channel-sum first; conv linear ->
// difference first; the two boundary pad rows/cols contribute 0 to the numerator;
// the 0.5 gradient coefficient and the 3 identical output channels fold into the scale.)
//
// R1 structure: one wave == one image row (64 lanes x float4 == 256 columns).
// All 18 global float4 loads issued into registers before any use (max MLP, no LDS,
// no barriers in the hot path). Horizontal neighbors via intra-wave shuffles.
// Grid 98*64 = 6272 blocks -> ~24 blocks/CU, no tail quantization.

#define W 256
#define NIMG 98
#define CH_STRIDE 65536   // 256*256

__global__ __launch_bounds__(256) void detail_loss_kernel(
    const float* __restrict__ x, const float* __restrict__ y,
    float* __restrict__ out) {
  const int tid  = threadIdx.x;
  const int lane = tid & 63;
  const int wv   = tid >> 6;              // 4 waves -> 4 consecutive rows
  const int n    = blockIdx.x >> 6;       // image index (64 row-groups per image)
  const int rg   = blockIdx.x & 63;
  const int row  = rg * 4 + wv;           // this wave's output row, 0..255

  const float* xb = x + (size_t)n * 3 * CH_STRIDE + (lane << 2);
  const float* yb = y + (size_t)n * 3 * CH_STRIDE + (lane << 2);

  // ---- Load raw rows r-1, r, r+1 for all 3 channels, both tensors (18 float4). ----
  float4 xr[3][3], yr[3][3];   // [row_off][channel]
  #pragma unroll
  for (int dr = 0; dr < 3; ++dr) {
    int r = row - 1 + dr;
    bool ok = (r >= 0) && (r < 256);       // wave-uniform branch
    #pragma unroll
    for (int c = 0; c < 3; ++c) {
      if (ok) {
        int off = c * CH_STRIDE + r * W;
        xr[dr][c] = *(const float4*)(xb + off);
        yr[dr][c] = *(const float4*)(yb + off);
      } else {
        xr[dr][c] = make_float4(0.f, 0.f, 0.f, 0.f);
        yr[dr][c] = make_float4(0.f, 0.f, 0.f, 0.f);
      }
    }
  }

  // ---- Channel-summed differences for the 3 rows. ----
  float4 Dm, D0, Dp;
  #pragma unroll
  for (int dr = 0; dr < 3; ++dr) {
    float4 d;
    d.x = (xr[dr][0].x - yr[dr][0].x) + (xr[dr][1].x - yr[dr][1].x) + (xr[dr][2].x - yr[dr][2].x);
    d.y = (xr[dr][0].y - yr[dr][0].y) + (xr[dr][1].y - yr[dr][1].y) + (xr[dr][2].y - yr[dr][2].y);
    d.z = (xr[dr][0].z - yr[dr][0].z) + (xr[dr][1].z - yr[dr][1].z) + (xr[dr][2].z - yr[dr][2].z);
    d.w = (xr[dr][0].w - yr[dr][0].w) + (xr[dr][1].w - yr[dr][1].w) + (xr[dr][2].w - yr[dr][2].w);
    if (dr == 0) Dm = d; else if (dr == 1) D0 = d; else Dp = d;
  }

  // ---- Horizontal neighbors across lanes (cols -1 and +4 of this thread's chunk). ----
  float left  = __shfl_up(D0.w, 1, 64);   // lane-1's col 4j-1
  float right = __shfl_down(D0.x, 1, 64); // lane+1's col 4j+4
  if (lane == 0)  left  = 0.f;            // image col -1 is zero pad
  if (lane == 63) right = 0.f;            // image col 256 is zero pad

  float acc = fabsf(D0.y - left)
            + fabsf(D0.z - D0.x)
            + fabsf(D0.w - D0.y)
            + fabsf(right - D0.z)
            + fabsf(Dp.x - Dm.x)
            + fabsf(Dp.y - Dm.y)
            + fabsf(Dp.z - Dm.z)
            + fabsf(Dp.w - Dm.w);

  // ---- Wave reduce (64 lanes), then cross-wave via tiny LDS, 1 atomic per block. ----
  #pragma unroll
  for (int off = 32; off > 0; off >>= 1)
    acc += __shfl_down(acc, off, 64);

  __shared__ float wsum[4];
  if (lane == 0) wsum[wv] = acc;
  __syncthreads();
  if (tid == 0) {
    float s = wsum[0] + wsum[1] + wsum[2] + wsum[3];
    atomicAdd(out, s * (0.25f / 6472704.0f));   // 0.25/(98*258*256)
  }
}

extern "C" void kernel_launch(void* const* d_in, const int* in_sizes, int n_in,
                              void* d_out, int out_size, void* d_ws, size_t ws_size,
                              hipStream_t stream) {
  const float* infer = (const float*)d_in[0];
  const float* ref   = (const float*)d_in[1];
  float* out = (float*)d_out;

  hipMemsetAsync(out, 0, sizeof(float), stream);   // d_out re-poisoned before every launch
  detail_loss_kernel<<<NIMG * 64, 256, 0, stream>>>(infer, ref, out);
}

// Round 3
// 173.463 us; speedup vs baseline: 1.2422x; 1.2422x over previous
//
#include <hip/hip_runtime.h>

// Detail_loss: loss = 0.25/(98*258*256) * sum_{n,h,w} ( |D[h][w+1]-D[h][w-1]| + |D[h+1][w]-D[h-1][w]| )
// where D[n,h,w] = sum_c (infer - ref)[n,c,h,w], zero outside [0,256)^2.
// (identical per-channel-pair kernels -> channel-sum first; conv linearity ->
// difference first; pad rows/cols contribute 0; scale folds the 0.5 coeff,
// 3 output channels, and the /(98*3*258*256) means.)
//
// R2 structure: single-wave blocks (no LDS, no barriers). One wave owns a TH=4
// row strip of one image (64 lanes x float4 = 256 cols), rolling 3-row register
// window for the vertical gradient, lane shuffles for horizontal. Per-block
// partial -> d_ws (plain store, zero contention), tiny stage-2 kernel reduces.

#define W 256
#define NIMG 98
#define CH_STRIDE 65536      // 256*256
#define TH 4
#define NSTRIP 64            // 256 / TH
#define NBLK (NIMG * NSTRIP) // 6272
#define SCALE (0.25f / 6472704.0f)   // 0.25/(98*258*256)

__device__ __forceinline__ float4 load_D_row(const float* __restrict__ xb,
                                             const float* __restrict__ yb, int r) {
  float4 d = make_float4(0.f, 0.f, 0.f, 0.f);
  if (r >= 0 && r < 256) {              // wave-uniform
    const int off = r * W;
    #pragma unroll
    for (int c = 0; c < 3; ++c) {
      float4 xv = *(const float4*)(xb + c * CH_STRIDE + off);
      float4 yv = *(const float4*)(yb + c * CH_STRIDE + off);
      d.x += xv.x - yv.x;
      d.y += xv.y - yv.y;
      d.z += xv.z - yv.z;
      d.w += xv.w - yv.w;
    }
  }
  return d;
}

__global__ __launch_bounds__(64) void detail_stage1(
    const float* __restrict__ x, const float* __restrict__ y,
    float* __restrict__ partial) {
  const int lane  = threadIdx.x;        // one wave per block
  const int b     = blockIdx.x;
  const int n     = b >> 6;             // image
  const int strip = b & 63;
  const int r0    = strip * TH;

  const float* xb = x + (size_t)n * 3 * CH_STRIDE + (lane << 2);
  const float* yb = y + (size_t)n * 3 * CH_STRIDE + (lane << 2);

  float4 Dm = load_D_row(xb, yb, r0 - 1);
  float4 D0 = load_D_row(xb, yb, r0);
  float acc = 0.f;

  #pragma unroll
  for (int i = 0; i < TH; ++i) {
    float4 Dp = load_D_row(xb, yb, r0 + i + 1);   // issues while row i computes
    float left  = __shfl_up(D0.w, 1, 64);         // col 4j-1 from lane-1
    float right = __shfl_down(D0.x, 1, 64);       // col 4j+4 from lane+1
    if (lane == 0)  left  = 0.f;                  // image col -1 zero pad
    if (lane == 63) right = 0.f;                  // image col 256 zero pad
    acc += fabsf(D0.y - left)  + fabsf(D0.z - D0.x)
         + fabsf(D0.w - D0.y)  + fabsf(right - D0.z)
         + fabsf(Dp.x - Dm.x)  + fabsf(Dp.y - Dm.y)
         + fabsf(Dp.z - Dm.z)  + fabsf(Dp.w - Dm.w);
    Dm = D0; D0 = Dp;
  }

  #pragma unroll
  for (int off = 32; off > 0; off >>= 1)
    acc += __shfl_down(acc, off, 64);
  if (lane == 0) partial[b] = acc;
}

// Fallback single-kernel variant (atomic) in case ws_size is too small.
__global__ __launch_bounds__(64) void detail_stage1_atomic(
    const float* __restrict__ x, const float* __restrict__ y,
    float* __restrict__ out) {
  const int lane  = threadIdx.x;
  const int b     = blockIdx.x;
  const int n     = b >> 6;
  const int strip = b & 63;
  const int r0    = strip * TH;
  const float* xb = x + (size_t)n * 3 * CH_STRIDE + (lane << 2);
  const float* yb = y + (size_t)n * 3 * CH_STRIDE + (lane << 2);
  float4 Dm = load_D_row(xb, yb, r0 - 1);
  float4 D0 = load_D_row(xb, yb, r0);
  float acc = 0.f;
  #pragma unroll
  for (int i = 0; i < TH; ++i) {
    float4 Dp = load_D_row(xb, yb, r0 + i + 1);
    float left  = __shfl_up(D0.w, 1, 64);
    float right = __shfl_down(D0.x, 1, 64);
    if (lane == 0)  left  = 0.f;
    if (lane == 63) right = 0.f;
    acc += fabsf(D0.y - left)  + fabsf(D0.z - D0.x)
         + fabsf(D0.w - D0.y)  + fabsf(right - D0.z)
         + fabsf(Dp.x - Dm.x)  + fabsf(Dp.y - Dm.y)
         + fabsf(Dp.z - Dm.z)  + fabsf(Dp.w - Dm.w);
    Dm = D0; D0 = Dp;
  }
  #pragma unroll
  for (int off = 32; off > 0; off >>= 1)
    acc += __shfl_down(acc, off, 64);
  if (lane == 0) atomicAdd(out, acc * SCALE);
}

__global__ __launch_bounds__(256) void detail_stage2(
    const float* __restrict__ partial, float* __restrict__ out) {
  float acc = 0.f;
  for (int i = threadIdx.x; i < NBLK; i += 256) acc += partial[i];
  #pragma unroll
  for (int off = 32; off > 0; off >>= 1)
    acc += __shfl_down(acc, off, 64);
  __shared__ float ws[4];
  if ((threadIdx.x & 63) == 0) ws[threadIdx.x >> 6] = acc;
  __syncthreads();
  if (threadIdx.x == 0) out[0] = (ws[0] + ws[1] + ws[2] + ws[3]) * SCALE;
}

extern "C" void kernel_launch(void* const* d_in, const int* in_sizes, int n_in,
                              void* d_out, int out_size, void* d_ws, size_t ws_size,
                              hipStream_t stream) {
  const float* infer = (const float*)d_in[0];
  const float* ref   = (const float*)d_in[1];
  float* out = (float*)d_out;

  if (ws_size >= NBLK * sizeof(float)) {
    float* partial = (float*)d_ws;
    detail_stage1<<<NBLK, 64, 0, stream>>>(infer, ref, partial);
    detail_stage2<<<1, 256, 0, stream>>>(partial, out);
  } else {
    hipMemsetAsync(out, 0, sizeof(float), stream);
    detail_stage1_atomic<<<NBLK, 64, 0, stream>>>(infer, ref, out);
  }
}